// Round 4
// baseline (90.581 us; speedup 1.0000x reference)
//
#include <hip/hip_runtime.h>
#include <math.h>

// Problem constants (setup_inputs: B=16, C=4, H=256, W=256, S=24)
constexpr int Hc = 256;
constexpr int Wc = 256;
constexpr float EPSf = 1e-6f;

__device__ __forceinline__ float comp(const float4& v, int p) {
    return p == 0 ? v.x : p == 1 ? v.y : p == 2 ? v.z : v.w;
}

// Branch-free acos for x in [0, 1): Abramowitz-Stegun 4.4.45, |err| <= 6.7e-5
// (tolerance is 1.8e-2). Raw v_sqrt_f32, no libm fixup sequence.
__device__ __forceinline__ float fast_acos01(float x) {
    float t = __builtin_amdgcn_sqrtf(1.0f - x);
    float p = fmaf(fmaf(fmaf(-0.0187293f, x, 0.0742610f), x, -0.2121144f),
                   x, 1.5707288f);
    return t * p;
}

__device__ __forceinline__ float fast_sqrt(float x) {
    return __builtin_amdgcn_sqrtf(x);   // single v_sqrt_f32 (~2 ulp)
}

// One thread = 4 consecutive pixels along w (one float4 quad).
// One wave (64 lanes) = one image row (64*4 = 256 = W).
// All global loads issued first; branch-free math throughout; per-block
// premultiplied contribution atomically added to out[0] (no reduce kernel).
template<int S>
__global__ __launch_bounds__(256, 4) void sym_loss_main(
    const float* __restrict__ qp,
    const float* __restrict__ qt,
    const float* __restrict__ syms,
    float* __restrict__ out,
    float cRot, float cGrad)
{
    int t    = blockIdx.x * 256 + threadIdx.x;
    int lane = t & 63;           // quad index within the row
    int row  = t >> 6;           // 0 .. B*H-1
    int b    = row >> 8;         // H = 256 rows per image
    int h    = row & (Hc - 1);
    int w0   = lane << 2;

    int idx0 = (b << 18) + (h << 8) + w0;   // channel-0 flat index
    // edge pad: squared differences make the direction sign irrelevant
    int dy = (h == Hc - 1) ? -Wc : Wc;      // wave-uniform
    // x-neighbor of element 3 (w0+3): value at w0+4, except lane 63
    // (w=255, edge) where the duplicated diff uses w=254 = idx+2.
    int xo = (lane == 63) ? 2 : 4;          // in-bounds for all lanes

    // ---- phase 1: issue every global load ----
    float4 Cp[4], Yp[4], Ct[4], Yt[4];
    float  xp[4], xt[4];
    #pragma unroll
    for (int c = 0; c < 4; ++c) {
        int idx = idx0 + (c << 16);
        Cp[c] = *(const float4*)(qp + idx);
        Yp[c] = *(const float4*)(qp + idx + dy);
        xp[c] = qp[idx + xo];
        Ct[c] = *(const float4*)(qt + idx);
        Yt[c] = *(const float4*)(qt + idx + dy);
        xt[c] = qt[idx + xo];
    }

    // ---- phase 2: gradient-magnitude term ----
    float gsum = 0.0f;
    #pragma unroll
    for (int c = 0; c < 4; ++c) {
        float4 C = Cp[c], Y = Yp[c], D = Ct[c], Z = Yt[c];
        float gx, gy, a, e;
        gx = C.y - C.x; gy = Y.x - C.x;
        a = fast_sqrt(fmaf(gx, gx, fmaf(gy, gy, EPSf)));
        gx = D.y - D.x; gy = Z.x - D.x;
        e = fast_sqrt(fmaf(gx, gx, fmaf(gy, gy, EPSf)));
        gsum += fabsf(a - e);

        gx = C.z - C.y; gy = Y.y - C.y;
        a = fast_sqrt(fmaf(gx, gx, fmaf(gy, gy, EPSf)));
        gx = D.z - D.y; gy = Z.y - D.y;
        e = fast_sqrt(fmaf(gx, gx, fmaf(gy, gy, EPSf)));
        gsum += fabsf(a - e);

        gx = C.w - C.z; gy = Y.z - C.z;
        a = fast_sqrt(fmaf(gx, gx, fmaf(gy, gy, EPSf)));
        gx = D.w - D.z; gy = Z.z - D.z;
        e = fast_sqrt(fmaf(gx, gx, fmaf(gy, gy, EPSf)));
        gsum += fabsf(a - e);

        gx = xp[c] - C.w; gy = Y.w - C.w;
        a = fast_sqrt(fmaf(gx, gx, fmaf(gy, gy, EPSf)));
        gx = xt[c] - D.w; gy = Z.w - D.w;
        e = fast_sqrt(fmaf(gx, gx, fmaf(gy, gy, EPSf)));
        gsum += fabsf(a - e);
    }

    // ---- phase 3: per-pixel relative quaternion (vector part negated) ----
    float rw[4], nx[4], ny[4], nz[4];
    #pragma unroll
    for (int p = 0; p < 4; ++p) {
        float a0 = comp(Cp[0], p), a1 = comp(Cp[1], p),
              a2 = comp(Cp[2], p), a3 = comp(Cp[3], p);
        float b0 = comp(Ct[0], p), b1 = comp(Ct[1], p),
              b2 = comp(Ct[2], p), b3 = comp(Ct[3], p);

        float ss1 = fmaf(a0, a0, fmaf(a1, a1, fmaf(a2, a2, a3 * a3)));
        float ss2 = fmaf(b0, b0, fmaf(b1, b1, fmaf(b2, b2, b3 * b3)));
        float i1 = __builtin_amdgcn_rsqf(ss1);   // ss >> eps^2 always here
        float i2 = __builtin_amdgcn_rsqf(ss2);
        float w1 = a0 * i1, x1 = a1 * i1, y1 = a2 * i1, z1 = a3 * i1;
        float w2 = b0 * i2, x2 = b1 * i2, y2 = b2 * i2, z2 = b3 * i2;

        rw[p] =  w2 * w1 + x2 * x1 + y2 * y1 + z2 * z1;
        float rx = -w2 * x1 + x2 * w1 - y2 * z1 + z2 * y1;
        float ry = -w2 * y1 + x2 * z1 + y2 * w1 - z2 * x1;
        float rz = -w2 * z1 - x2 * y1 + y2 * x1 + z2 * w1;
        nx[p] = -rx; ny[p] = -ry; nz[p] = -rz;   // signs [1,-1,-1,-1]
    }

    // ---- phase 4: sym search; wave-uniform scalar loads, fully unrolled ----
    const float4* __restrict__ sv4 = (const float4*)syms;
    float maxw[4] = {0.f, 0.f, 0.f, 0.f};
    #pragma unroll
    for (int s = 0; s < S; ++s) {
        float4 sv = sv4[s];
        #pragma unroll
        for (int p = 0; p < 4; ++p) {
            float d = fmaf(nz[p], sv.w,
                      fmaf(ny[p], sv.z,
                      fmaf(nx[p], sv.y, rw[p] * sv.x)));
            maxw[p] = fmaxf(maxw[p], fabsf(d));
        }
    }
    float rot = 0.0f;
    #pragma unroll
    for (int p = 0; p < 4; ++p)
        rot += fast_acos01(fminf(maxw[p], 1.0f - EPSf));
    // (x2 for the 2*acos is folded into cRot)

    // ---- phase 5: block reduce, one premultiplied atomic per block ----
    #pragma unroll
    for (int off = 32; off > 0; off >>= 1) {
        rot  += __shfl_down(rot,  off, 64);
        gsum += __shfl_down(gsum, off, 64);
    }
    __shared__ float s_r[4], s_g[4];
    int wid = threadIdx.x >> 6;
    if ((threadIdx.x & 63) == 0) { s_r[wid] = rot; s_g[wid] = gsum; }
    __syncthreads();
    if (threadIdx.x == 0) {
        float r = s_r[0] + s_r[1] + s_r[2] + s_r[3];
        float g = s_g[0] + s_g[1] + s_g[2] + s_g[3];
        atomicAdd(out, fmaf(r, cRot, g * cGrad));
    }
}

// Generic-S fallback (runtime sym loop), same math
__global__ __launch_bounds__(256) void sym_loss_generic(
    const float* __restrict__ qp,
    const float* __restrict__ qt,
    const float* __restrict__ syms,
    int S,
    float* __restrict__ out,
    float cRot, float cGrad)
{
    int t    = blockIdx.x * 256 + threadIdx.x;
    int lane = t & 63;
    int row  = t >> 6;
    int b    = row >> 8;
    int h    = row & (Hc - 1);
    int w0   = lane << 2;
    int idx0 = (b << 18) + (h << 8) + w0;
    int dy = (h == Hc - 1) ? -Wc : Wc;
    int xo = (lane == 63) ? 2 : 4;

    float4 Cp[4], Yp[4], Ct[4], Yt[4];
    float  xp[4], xt[4];
    #pragma unroll
    for (int c = 0; c < 4; ++c) {
        int idx = idx0 + (c << 16);
        Cp[c] = *(const float4*)(qp + idx);
        Yp[c] = *(const float4*)(qp + idx + dy);
        xp[c] = qp[idx + xo];
        Ct[c] = *(const float4*)(qt + idx);
        Yt[c] = *(const float4*)(qt + idx + dy);
        xt[c] = qt[idx + xo];
    }
    float gsum = 0.0f;
    #pragma unroll
    for (int c = 0; c < 4; ++c) {
        float4 C = Cp[c], Y = Yp[c], D = Ct[c], Z = Yt[c];
        float gx, gy, a, e;
        gx = C.y - C.x; gy = Y.x - C.x;
        a = fast_sqrt(fmaf(gx, gx, fmaf(gy, gy, EPSf)));
        gx = D.y - D.x; gy = Z.x - D.x;
        e = fast_sqrt(fmaf(gx, gx, fmaf(gy, gy, EPSf)));
        gsum += fabsf(a - e);
        gx = C.z - C.y; gy = Y.y - C.y;
        a = fast_sqrt(fmaf(gx, gx, fmaf(gy, gy, EPSf)));
        gx = D.z - D.y; gy = Z.y - D.y;
        e = fast_sqrt(fmaf(gx, gx, fmaf(gy, gy, EPSf)));
        gsum += fabsf(a - e);
        gx = C.w - C.z; gy = Y.z - C.z;
        a = fast_sqrt(fmaf(gx, gx, fmaf(gy, gy, EPSf)));
        gx = D.w - D.z; gy = Z.z - D.z;
        e = fast_sqrt(fmaf(gx, gx, fmaf(gy, gy, EPSf)));
        gsum += fabsf(a - e);
        gx = xp[c] - C.w; gy = Y.w - C.w;
        a = fast_sqrt(fmaf(gx, gx, fmaf(gy, gy, EPSf)));
        gx = xt[c] - D.w; gy = Z.w - D.w;
        e = fast_sqrt(fmaf(gx, gx, fmaf(gy, gy, EPSf)));
        gsum += fabsf(a - e);
    }
    float rw[4], nx[4], ny[4], nz[4];
    #pragma unroll
    for (int p = 0; p < 4; ++p) {
        float a0 = comp(Cp[0], p), a1 = comp(Cp[1], p),
              a2 = comp(Cp[2], p), a3 = comp(Cp[3], p);
        float b0 = comp(Ct[0], p), b1 = comp(Ct[1], p),
              b2 = comp(Ct[2], p), b3 = comp(Ct[3], p);
        float ss1 = fmaf(a0, a0, fmaf(a1, a1, fmaf(a2, a2, a3 * a3)));
        float ss2 = fmaf(b0, b0, fmaf(b1, b1, fmaf(b2, b2, b3 * b3)));
        float i1 = __builtin_amdgcn_rsqf(ss1);
        float i2 = __builtin_amdgcn_rsqf(ss2);
        float w1 = a0 * i1, x1 = a1 * i1, y1 = a2 * i1, z1 = a3 * i1;
        float w2 = b0 * i2, x2 = b1 * i2, y2 = b2 * i2, z2 = b3 * i2;
        rw[p] =  w2 * w1 + x2 * x1 + y2 * y1 + z2 * z1;
        float rx = -w2 * x1 + x2 * w1 - y2 * z1 + z2 * y1;
        float ry = -w2 * y1 + x2 * z1 + y2 * w1 - z2 * x1;
        float rz = -w2 * z1 - x2 * y1 + y2 * x1 + z2 * w1;
        nx[p] = -rx; ny[p] = -ry; nz[p] = -rz;
    }
    const float4* __restrict__ sv4 = (const float4*)syms;
    float maxw[4] = {0.f, 0.f, 0.f, 0.f};
    for (int s = 0; s < S; ++s) {
        float4 sv = sv4[s];
        #pragma unroll
        for (int p = 0; p < 4; ++p) {
            float d = fmaf(nz[p], sv.w,
                      fmaf(ny[p], sv.z,
                      fmaf(nx[p], sv.y, rw[p] * sv.x)));
            maxw[p] = fmaxf(maxw[p], fabsf(d));
        }
    }
    float rot = 0.0f;
    #pragma unroll
    for (int p = 0; p < 4; ++p)
        rot += fast_acos01(fminf(maxw[p], 1.0f - EPSf));
    #pragma unroll
    for (int off = 32; off > 0; off >>= 1) {
        rot  += __shfl_down(rot,  off, 64);
        gsum += __shfl_down(gsum, off, 64);
    }
    __shared__ float s_r[4], s_g[4];
    int wid = threadIdx.x >> 6;
    if ((threadIdx.x & 63) == 0) { s_r[wid] = rot; s_g[wid] = gsum; }
    __syncthreads();
    if (threadIdx.x == 0) {
        float r = s_r[0] + s_r[1] + s_r[2] + s_r[3];
        float g = s_g[0] + s_g[1] + s_g[2] + s_g[3];
        atomicAdd(out, fmaf(r, cRot, g * cGrad));
    }
}

extern "C" void kernel_launch(void* const* d_in, const int* in_sizes, int n_in,
                              void* d_out, int out_size, void* d_ws, size_t ws_size,
                              hipStream_t stream)
{
    const float* qp   = (const float*)d_in[0];
    const float* qt   = (const float*)d_in[1];
    const float* syms = (const float*)d_in[2];
    float* out = (float*)d_out;

    int S  = in_sizes[2] / 4;        // 24
    int NP = in_sizes[0] / 4;        // B*H*W = 1,048,576 pixels
    int nthreads = NP / 4;           // 4 pixels per thread
    int nblocks  = nthreads / 256;   // 1024

    // loss = (2*sum_acos)/NP + 0.05*sum_grad/(4*NP); weights premultiplied
    float cRot  = (float)(2.0 / (double)NP);
    float cGrad = (float)(0.05 / ((double)NP * 4.0));

    hipMemsetAsync(out, 0, sizeof(float), stream);   // atomic accumulator

    if (S == 24) {
        sym_loss_main<24><<<nblocks, 256, 0, stream>>>(qp, qt, syms, out,
                                                       cRot, cGrad);
    } else {
        sym_loss_generic<<<nblocks, 256, 0, stream>>>(qp, qt, syms, S, out,
                                                      cRot, cGrad);
    }
}

// Round 5
// 88.845 us; speedup vs baseline: 1.0195x; 1.0195x over previous
//
#include <hip/hip_runtime.h>
#include <math.h>

// Problem constants (setup_inputs: B=16, C=4, H=256, W=256, S=24)
constexpr int Hc = 256;
constexpr int Wc = 256;
constexpr float EPSf = 1e-6f;

__device__ __forceinline__ float comp(const float4& v, int p) {
    return p == 0 ? v.x : p == 1 ? v.y : p == 2 ? v.z : v.w;
}

// Branch-free acos for x in [0,1): Abramowitz-Stegun 4.4.45, |err|<=6.7e-5
// (tolerance 1.8e-2). Raw v_sqrt_f32.
__device__ __forceinline__ float fast_acos01(float x) {
    float t = __builtin_amdgcn_sqrtf(1.0f - x);
    float p = fmaf(fmaf(fmaf(-0.0187293f, x, 0.0742610f), x, -0.2121144f),
                   x, 1.5707288f);
    return t * p;
}

__device__ __forceinline__ float fast_sqrt(float x) {
    return __builtin_amdgcn_sqrtf(x);   // single v_sqrt_f32 (~2 ulp)
}

// Block = 4 consecutive rows of one image (256 threads, wave w = row w).
// Thread = 4 consecutive pixels (one float4) per channel.
// Center rows staged in LDS; y-neighbors for waves 0-2 read from LDS
// (wave w+1's row), wave 3 fetches its y-row from global. x-neighbors via
// ds_read_b32 at w0+4 (w0+2 at the lane-63 edge: exact edge-pad value since
// diffs enter squared). Epilogue: one float2 partial per block + reduce
// kernel (1024 same-address atomics measured as a serialized tail in R4).
template<int S>
__global__ __launch_bounds__(256, 4) void sym_loss_main(
    const float* __restrict__ qp,
    const float* __restrict__ qt,
    const float* __restrict__ syms,
    float2* __restrict__ partial)
{
    // [tensor 0/1][channel 0..3][row-in-block 0..3][w 0..255]
    __shared__ float lds[2 * 4 * 4 * 256];   // 32 KB

    int tid  = threadIdx.x;
    int lane = tid & 63;
    int wid  = tid >> 6;                 // row within block
    int row  = (blockIdx.x << 2) + wid;  // global row = b*256 + h
    int b    = row >> 8;
    int h    = row & (Hc - 1);
    int w0   = lane << 2;

    int idx0 = (b << 18) + (h << 8) + w0;    // channel-0 flat index
    int dy   = (h == Hc - 1) ? -Wc : Wc;     // only used by wid==3
    // x-neighbor of element 3: w0+4; lane 63 (w=255 edge) -> w=254 = w0+2
    int xw   = w0 + ((lane == 63) ? 2 : 4);

    // ---- phase 1: global loads (center always; y-row only wave 3) ----
    float4 Cp[4], Ct[4], Yp3[4], Yt3[4];
    #pragma unroll
    for (int c = 0; c < 4; ++c) {
        int idx = idx0 + (c << 16);
        Cp[c] = *(const float4*)(qp + idx);
        Ct[c] = *(const float4*)(qt + idx);
    }
    if (wid == 3) {
        #pragma unroll
        for (int c = 0; c < 4; ++c) {
            int idx = idx0 + (c << 16) + dy;
            Yp3[c] = *(const float4*)(qp + idx);
            Yt3[c] = *(const float4*)(qt + idx);
        }
    }

    // ---- phase 2: stage center rows to LDS ----
    #pragma unroll
    for (int c = 0; c < 4; ++c) {
        *(float4*)&lds[(((0 * 4 + c) * 4 + wid) << 8) + w0] = Cp[c];
        *(float4*)&lds[(((1 * 4 + c) * 4 + wid) << 8) + w0] = Ct[c];
    }
    __syncthreads();

    // ---- phase 3: gradient-magnitude term ----
    float gsum = 0.0f;
    #pragma unroll
    for (int c = 0; c < 4; ++c) {
        float4 C = Cp[c], D = Ct[c];
        float4 Y, Z;
        if (wid < 3) {   // wave-uniform branch
            Y = *(const float4*)&lds[(((0 * 4 + c) * 4 + wid + 1) << 8) + w0];
            Z = *(const float4*)&lds[(((1 * 4 + c) * 4 + wid + 1) << 8) + w0];
        } else {
            Y = Yp3[c]; Z = Yt3[c];
        }
        float xp = lds[(((0 * 4 + c) * 4 + wid) << 8) + xw];
        float xt = lds[(((1 * 4 + c) * 4 + wid) << 8) + xw];

        float gx, gy, a, e;
        gx = C.y - C.x; gy = Y.x - C.x;
        a = fast_sqrt(fmaf(gx, gx, fmaf(gy, gy, EPSf)));
        gx = D.y - D.x; gy = Z.x - D.x;
        e = fast_sqrt(fmaf(gx, gx, fmaf(gy, gy, EPSf)));
        gsum += fabsf(a - e);

        gx = C.z - C.y; gy = Y.y - C.y;
        a = fast_sqrt(fmaf(gx, gx, fmaf(gy, gy, EPSf)));
        gx = D.z - D.y; gy = Z.y - D.y;
        e = fast_sqrt(fmaf(gx, gx, fmaf(gy, gy, EPSf)));
        gsum += fabsf(a - e);

        gx = C.w - C.z; gy = Y.z - C.z;
        a = fast_sqrt(fmaf(gx, gx, fmaf(gy, gy, EPSf)));
        gx = D.w - D.z; gy = Z.z - D.z;
        e = fast_sqrt(fmaf(gx, gx, fmaf(gy, gy, EPSf)));
        gsum += fabsf(a - e);

        gx = xp - C.w;  gy = Y.w - C.w;
        a = fast_sqrt(fmaf(gx, gx, fmaf(gy, gy, EPSf)));
        gx = xt - D.w;  gy = Z.w - D.w;
        e = fast_sqrt(fmaf(gx, gx, fmaf(gy, gy, EPSf)));
        gsum += fabsf(a - e);
    }

    // ---- phase 4: per-pixel relative quaternion (vector part negated) ----
    float rw[4], nx[4], ny[4], nz[4];
    #pragma unroll
    for (int p = 0; p < 4; ++p) {
        float a0 = comp(Cp[0], p), a1 = comp(Cp[1], p),
              a2 = comp(Cp[2], p), a3 = comp(Cp[3], p);
        float b0 = comp(Ct[0], p), b1 = comp(Ct[1], p),
              b2 = comp(Ct[2], p), b3 = comp(Ct[3], p);

        float ss1 = fmaf(a0, a0, fmaf(a1, a1, fmaf(a2, a2, a3 * a3)));
        float ss2 = fmaf(b0, b0, fmaf(b1, b1, fmaf(b2, b2, b3 * b3)));
        float i1 = __builtin_amdgcn_rsqf(ss1);   // ss >> eps^2 here
        float i2 = __builtin_amdgcn_rsqf(ss2);
        float w1 = a0 * i1, x1 = a1 * i1, y1 = a2 * i1, z1 = a3 * i1;
        float w2 = b0 * i2, x2 = b1 * i2, y2 = b2 * i2, z2 = b3 * i2;

        rw[p] =  w2 * w1 + x2 * x1 + y2 * y1 + z2 * z1;
        float rx = -w2 * x1 + x2 * w1 - y2 * z1 + z2 * y1;
        float ry = -w2 * y1 + x2 * z1 + y2 * w1 - z2 * x1;
        float rz = -w2 * z1 - x2 * y1 + y2 * x1 + z2 * w1;
        nx[p] = -rx; ny[p] = -ry; nz[p] = -rz;   // signs [1,-1,-1,-1]
    }

    // ---- phase 5: sym search (wave-uniform scalar syms, fully unrolled) ----
    const float4* __restrict__ sv4 = (const float4*)syms;
    float maxw[4] = {0.f, 0.f, 0.f, 0.f};
    #pragma unroll
    for (int s = 0; s < S; ++s) {
        float4 sv = sv4[s];
        #pragma unroll
        for (int p = 0; p < 4; ++p) {
            float d = fmaf(nz[p], sv.w,
                      fmaf(ny[p], sv.z,
                      fmaf(nx[p], sv.y, rw[p] * sv.x)));
            maxw[p] = fmaxf(maxw[p], fabsf(d));
        }
    }
    float rot = 0.0f;
    #pragma unroll
    for (int p = 0; p < 4; ++p)
        rot += fast_acos01(fminf(maxw[p], 1.0f - EPSf));
    // (x2 of 2*acos folded into the reduce kernel's scale)

    // ---- phase 6: block reduce -> one float2 partial ----
    #pragma unroll
    for (int off = 32; off > 0; off >>= 1) {
        rot  += __shfl_down(rot,  off, 64);
        gsum += __shfl_down(gsum, off, 64);
    }
    __shared__ float s_r[4], s_g[4];
    if (lane == 0) { s_r[wid] = rot; s_g[wid] = gsum; }
    __syncthreads();
    if (tid == 0) {
        float2 o;
        o.x = s_r[0] + s_r[1] + s_r[2] + s_r[3];
        o.y = s_g[0] + s_g[1] + s_g[2] + s_g[3];
        partial[blockIdx.x] = o;
    }
}

// Generic-S fallback: no LDS sharing, direct loads (round-3 structure)
__global__ __launch_bounds__(256) void sym_loss_generic(
    const float* __restrict__ qp,
    const float* __restrict__ qt,
    const float* __restrict__ syms,
    int S,
    float2* __restrict__ partial)
{
    int t    = blockIdx.x * 256 + threadIdx.x;
    int lane = t & 63;
    int row  = t >> 6;
    int b    = row >> 8;
    int h    = row & (Hc - 1);
    int w0   = lane << 2;
    int idx0 = (b << 18) + (h << 8) + w0;
    int dy = (h == Hc - 1) ? -Wc : Wc;
    int xo = (lane == 63) ? 2 : 4;

    float4 Cp[4], Yp[4], Ct[4], Yt[4];
    float  xp[4], xt[4];
    #pragma unroll
    for (int c = 0; c < 4; ++c) {
        int idx = idx0 + (c << 16);
        Cp[c] = *(const float4*)(qp + idx);
        Yp[c] = *(const float4*)(qp + idx + dy);
        xp[c] = qp[idx + xo];
        Ct[c] = *(const float4*)(qt + idx);
        Yt[c] = *(const float4*)(qt + idx + dy);
        xt[c] = qt[idx + xo];
    }
    float gsum = 0.0f;
    #pragma unroll
    for (int c = 0; c < 4; ++c) {
        float4 C = Cp[c], Y = Yp[c], D = Ct[c], Z = Yt[c];
        float gx, gy, a, e;
        gx = C.y - C.x; gy = Y.x - C.x;
        a = fast_sqrt(fmaf(gx, gx, fmaf(gy, gy, EPSf)));
        gx = D.y - D.x; gy = Z.x - D.x;
        e = fast_sqrt(fmaf(gx, gx, fmaf(gy, gy, EPSf)));
        gsum += fabsf(a - e);
        gx = C.z - C.y; gy = Y.y - C.y;
        a = fast_sqrt(fmaf(gx, gx, fmaf(gy, gy, EPSf)));
        gx = D.z - D.y; gy = Z.y - D.y;
        e = fast_sqrt(fmaf(gx, gx, fmaf(gy, gy, EPSf)));
        gsum += fabsf(a - e);
        gx = C.w - C.z; gy = Y.z - C.z;
        a = fast_sqrt(fmaf(gx, gx, fmaf(gy, gy, EPSf)));
        gx = D.w - D.z; gy = Z.z - D.z;
        e = fast_sqrt(fmaf(gx, gx, fmaf(gy, gy, EPSf)));
        gsum += fabsf(a - e);
        gx = xp[c] - C.w; gy = Y.w - C.w;
        a = fast_sqrt(fmaf(gx, gx, fmaf(gy, gy, EPSf)));
        gx = xt[c] - D.w; gy = Z.w - D.w;
        e = fast_sqrt(fmaf(gx, gx, fmaf(gy, gy, EPSf)));
        gsum += fabsf(a - e);
    }
    float rw[4], nx[4], ny[4], nz[4];
    #pragma unroll
    for (int p = 0; p < 4; ++p) {
        float a0 = comp(Cp[0], p), a1 = comp(Cp[1], p),
              a2 = comp(Cp[2], p), a3 = comp(Cp[3], p);
        float b0 = comp(Ct[0], p), b1 = comp(Ct[1], p),
              b2 = comp(Ct[2], p), b3 = comp(Ct[3], p);
        float ss1 = fmaf(a0, a0, fmaf(a1, a1, fmaf(a2, a2, a3 * a3)));
        float ss2 = fmaf(b0, b0, fmaf(b1, b1, fmaf(b2, b2, b3 * b3)));
        float i1 = __builtin_amdgcn_rsqf(ss1);
        float i2 = __builtin_amdgcn_rsqf(ss2);
        float w1 = a0 * i1, x1 = a1 * i1, y1 = a2 * i1, z1 = a3 * i1;
        float w2 = b0 * i2, x2 = b1 * i2, y2 = b2 * i2, z2 = b3 * i2;
        rw[p] =  w2 * w1 + x2 * x1 + y2 * y1 + z2 * z1;
        float rx = -w2 * x1 + x2 * w1 - y2 * z1 + z2 * y1;
        float ry = -w2 * y1 + x2 * z1 + y2 * w1 - z2 * x1;
        float rz = -w2 * z1 - x2 * y1 + y2 * x1 + z2 * w1;
        nx[p] = -rx; ny[p] = -ry; nz[p] = -rz;
    }
    const float4* __restrict__ sv4 = (const float4*)syms;
    float maxw[4] = {0.f, 0.f, 0.f, 0.f};
    for (int s = 0; s < S; ++s) {
        float4 sv = sv4[s];
        #pragma unroll
        for (int p = 0; p < 4; ++p) {
            float d = fmaf(nz[p], sv.w,
                      fmaf(ny[p], sv.z,
                      fmaf(nx[p], sv.y, rw[p] * sv.x)));
            maxw[p] = fmaxf(maxw[p], fabsf(d));
        }
    }
    float rot = 0.0f;
    #pragma unroll
    for (int p = 0; p < 4; ++p)
        rot += fast_acos01(fminf(maxw[p], 1.0f - EPSf));
    #pragma unroll
    for (int off = 32; off > 0; off >>= 1) {
        rot  += __shfl_down(rot,  off, 64);
        gsum += __shfl_down(gsum, off, 64);
    }
    __shared__ float s_r[4], s_g[4];
    int wid = threadIdx.x >> 6;
    if ((threadIdx.x & 63) == 0) { s_r[wid] = rot; s_g[wid] = gsum; }
    __syncthreads();
    if (threadIdx.x == 0) {
        float2 o;
        o.x = s_r[0] + s_r[1] + s_r[2] + s_r[3];
        o.y = s_g[0] + s_g[1] + s_g[2] + s_g[3];
        partial[blockIdx.x] = o;
    }
}

__global__ __launch_bounds__(256) void sym_loss_reduce(
    const float2* __restrict__ partial, int nblocks,
    float* __restrict__ out, double cRot, double cGrad)
{
    double r = 0.0, g = 0.0;
    for (int i = threadIdx.x; i < nblocks; i += 256) {
        float2 p = partial[i];
        r += (double)p.x;
        g += (double)p.y;
    }
    #pragma unroll
    for (int off = 32; off > 0; off >>= 1) {
        r += __shfl_down(r, off, 64);
        g += __shfl_down(g, off, 64);
    }
    __shared__ double s_r[4], s_g[4];
    int wid = threadIdx.x >> 6;
    if ((threadIdx.x & 63) == 0) { s_r[wid] = r; s_g[wid] = g; }
    __syncthreads();
    if (threadIdx.x == 0) {
        double rr = s_r[0] + s_r[1] + s_r[2] + s_r[3];
        double gg = s_g[0] + s_g[1] + s_g[2] + s_g[3];
        out[0] = (float)(rr * cRot + gg * cGrad);
    }
}

extern "C" void kernel_launch(void* const* d_in, const int* in_sizes, int n_in,
                              void* d_out, int out_size, void* d_ws, size_t ws_size,
                              hipStream_t stream)
{
    const float* qp   = (const float*)d_in[0];
    const float* qt   = (const float*)d_in[1];
    const float* syms = (const float*)d_in[2];

    int S  = in_sizes[2] / 4;        // 24
    int NP = in_sizes[0] / 4;        // B*H*W = 1,048,576 pixels

    float2* partial = (float2*)d_ws; // every slot written each call

    // loss = (2*sum_acos)/NP + 0.05*sum_grad/(4*NP)
    double cRot  = 2.0 / (double)NP;
    double cGrad = 0.05 / ((double)NP * 4.0);

    int nblocks;
    if (S == 24) {
        nblocks = NP / 1024;         // 4 rows * 256 px per block = 1024
        sym_loss_main<24><<<nblocks, 256, 0, stream>>>(qp, qt, syms, partial);
    } else {
        nblocks = (NP / 4) / 256;
        sym_loss_generic<<<nblocks, 256, 0, stream>>>(qp, qt, syms, S, partial);
    }

    sym_loss_reduce<<<1, 256, 0, stream>>>(partial, nblocks, (float*)d_out,
                                           cRot, cGrad);
}